// Round 1
// baseline (3220.931 us; speedup 1.0000x reference)
//
#include <hip/hip_runtime.h>
#include <hip/hip_bf16.h>

#define NN 89250
#define NE 899756
#define INF_ 500
#define HID 256
#define NCLS 7

// ---------------- CSR build ----------------
__global__ void hist_kernel(const int* __restrict__ dst, int* __restrict__ cnt, int E) {
    int e = blockIdx.x * 256 + threadIdx.x;
    if (e < E) atomicAdd(&cnt[dst[e]], 1);
}

__global__ __launch_bounds__(1024) void scan_kernel(const int* __restrict__ cnt,
                                                    int* __restrict__ offs,
                                                    float* __restrict__ invc, int N) {
    __shared__ int sd[1024];
    __shared__ int s_run;
    int tid = threadIdx.x;
    if (tid == 0) s_run = 0;
    __syncthreads();
    int nChunks = (N + 1023) / 1024;
    for (int ch = 0; ch < nChunks; ch++) {
        int i = ch * 1024 + tid;
        int v = (i < N) ? cnt[i] : 0;
        sd[tid] = v;
        __syncthreads();
        for (int off = 1; off < 1024; off <<= 1) {
            int add = (tid >= off) ? sd[tid - off] : 0;
            __syncthreads();
            sd[tid] += add;
            __syncthreads();
        }
        int incl = sd[tid];
        int run = s_run;
        if (i < N) {
            offs[i] = run + incl - v;           // exclusive prefix
            invc[i] = 1.0f / fmaxf((float)v, 1.0f);
        }
        __syncthreads();
        if (tid == 1023) s_run = run + sd[1023];
        __syncthreads();
    }
    if (tid == 0) offs[N] = s_run;
}

__global__ void cursor_init(const int* __restrict__ offs, int* __restrict__ cursor, int N) {
    int i = blockIdx.x * 256 + threadIdx.x;
    if (i < N) cursor[i] = offs[i];
}

__global__ void scatter_kernel(const int* __restrict__ src, const int* __restrict__ dst,
                               const float* __restrict__ w, int* __restrict__ cursor,
                               int* __restrict__ csr_src, float* __restrict__ csr_w, int E) {
    int e = blockIdx.x * 256 + threadIdx.x;
    if (e < E) {
        int d = dst[e];
        int pos = atomicAdd(&cursor[d], 1);
        csr_src[pos] = src[e];
        csr_w[pos] = w[e];
    }
}

// ---------------- GEMM: C[N,512] = A[N,K] @ [W_top | W_bot], bias on first half ----------------
// W is [2K, 256] row-major. Output col j<256: sum_k A[n,k]*W[k,j] + bias[j]  (the "s" half)
//                             col j>=256:     sum_k A[n,k]*W[K+k, j-256]     (the "t" half)
__global__ __launch_bounds__(256) void gemm_concat(const float* __restrict__ A,
                                                   const float* __restrict__ W,
                                                   const float* __restrict__ bias,
                                                   float* __restrict__ C, int N, int K) {
    __shared__ float As[64][17];   // padded: avoid 4-way conflict on column reads
    __shared__ float Bs[16][64];
    int row0 = blockIdx.x * 64;
    int col0 = blockIdx.y * 64;            // 0..448
    int half = (col0 >= 256) ? 1 : 0;
    const float* Wbase = W + (half ? (size_t)K * 256 : 0);
    int wcol0 = col0 & 255;
    int tid = threadIdx.x;
    int tx = tid & 15, ty = tid >> 4;
    float acc[4][4] = {};
    for (int k0 = 0; k0 < K; k0 += 16) {
#pragma unroll
        for (int p = 0; p < 4; p++) {
            int li = tid + p * 256;
            int r = li >> 4, c = li & 15;
            int gr = row0 + r, gc = k0 + c;
            As[r][c] = (gr < N && gc < K) ? A[(size_t)gr * K + gc] : 0.f;
        }
#pragma unroll
        for (int p = 0; p < 4; p++) {
            int li = tid + p * 256;
            int kk = li >> 6, j = li & 63;
            int gk = k0 + kk;
            Bs[kk][j] = (gk < K) ? Wbase[(size_t)gk * 256 + wcol0 + j] : 0.f;
        }
        __syncthreads();
#pragma unroll
        for (int kk = 0; kk < 16; kk++) {
            float a[4], b[4];
#pragma unroll
            for (int i = 0; i < 4; i++) a[i] = As[4 * ty + i][kk];
            float4 bv = *(const float4*)&Bs[kk][4 * tx];
            b[0] = bv.x; b[1] = bv.y; b[2] = bv.z; b[3] = bv.w;
#pragma unroll
            for (int i = 0; i < 4; i++)
#pragma unroll
                for (int j = 0; j < 4; j++) acc[i][j] += a[i] * b[j];
        }
        __syncthreads();
    }
#pragma unroll
    for (int i = 0; i < 4; i++) {
        int gr = row0 + 4 * ty + i;
        if (gr < N) {
            float4 v = make_float4(acc[i][0], acc[i][1], acc[i][2], acc[i][3]);
            int gc = col0 + 4 * tx;
            if (!half) {
                v.x += bias[gc + 0]; v.y += bias[gc + 1];
                v.z += bias[gc + 2]; v.w += bias[gc + 3];
            }
            *(float4*)&C[(size_t)gr * 512 + gc] = v;
        }
    }
}

// ---------------- aggregate + relu: act[n,f] = relu(s[n,f] + (sum_e w_e * t[src_e,f]) / cnt[n]) ----------------
__global__ __launch_bounds__(256) void agg_relu_kernel(const float* __restrict__ st,
                                                       const int* __restrict__ offs,
                                                       const int* __restrict__ csr_src,
                                                       const float* __restrict__ csr_w,
                                                       const float* __restrict__ invc,
                                                       float* __restrict__ act, int N) {
    int n = blockIdx.x;
    int f = threadIdx.x;
    int beg = offs[n], end = offs[n + 1];
    float acc = 0.f;
    for (int j = beg; j < end; j++) {
        int s = csr_src[j];
        float w = csr_w[j];
        acc += st[(size_t)s * 512 + 256 + f] * w;
    }
    float v = st[(size_t)n * 512 + f] + acc * invc[n];
    act[(size_t)n * 256 + f] = fmaxf(v, 0.f);
}

// ---------------- logits += act @ Wl_chunk  (Wl_chunk: [256,7] row-major) ----------------
__global__ __launch_bounds__(256) void logits_add_kernel(const float* __restrict__ act,
                                                         const float* __restrict__ Wlc,
                                                         float* __restrict__ logits, int N) {
    __shared__ float sW[HID * NCLS];
    int tid = threadIdx.x;
    for (int idx = tid; idx < HID * NCLS; idx += 256) sW[idx] = Wlc[idx];
    __syncthreads();
    int wave = tid >> 6, lane = tid & 63;
    int n = blockIdx.x * 4 + wave;
    if (n >= N) return;
    float p[NCLS] = {};
#pragma unroll
    for (int r = 0; r < 4; r++) {
        int fidx = r * 64 + lane;
        float a = act[(size_t)n * HID + fidx];
#pragma unroll
        for (int c = 0; c < NCLS; c++) p[c] += a * sW[fidx * NCLS + c];
    }
#pragma unroll
    for (int c = 0; c < NCLS; c++) {
#pragma unroll
        for (int off = 32; off >= 1; off >>= 1) p[c] += __shfl_xor(p[c], off);
    }
    if (lane < NCLS) logits[(size_t)n * NCLS + lane] += p[lane];
}

// ---------------- final: out = log_softmax(logits + bl) ----------------
__global__ void logsoftmax_kernel(const float* __restrict__ logits, const float* __restrict__ bl,
                                  float* __restrict__ out, int N) {
    int n = blockIdx.x * 256 + threadIdx.x;
    if (n >= N) return;
    float l[NCLS];
    float m = -1e30f;
#pragma unroll
    for (int c = 0; c < NCLS; c++) {
        l[c] = logits[(size_t)n * NCLS + c] + bl[c];
        m = fmaxf(m, l[c]);
    }
    float s = 0.f;
#pragma unroll
    for (int c = 0; c < NCLS; c++) s += expf(l[c] - m);
    float lse = m + logf(s);
#pragma unroll
    for (int c = 0; c < NCLS; c++) out[(size_t)n * NCLS + c] = l[c] - lse;
}

extern "C" void kernel_launch(void* const* d_in, const int* in_sizes, int n_in,
                              void* d_out, int out_size, void* d_ws, size_t ws_size,
                              hipStream_t stream) {
    const float* x  = (const float*)d_in[0];
    const int*   ei = (const int*)d_in[1];
    const float* ew = (const float*)d_in[2];
    const float* W1 = (const float*)d_in[3];
    const float* b1 = (const float*)d_in[4];
    const float* W2 = (const float*)d_in[5];
    const float* b2 = (const float*)d_in[6];
    const float* W3 = (const float*)d_in[7];
    const float* b3 = (const float*)d_in[8];
    const float* Wl = (const float*)d_in[9];
    const float* bl = (const float*)d_in[10];
    float* out = (float*)d_out;

    const int N = NN, E = NE;
    const int* src = ei;
    const int* dst = ei + E;

    char* p = (char*)d_ws;
    auto alloc = [&](size_t bytes) {
        void* r = (void*)p;
        p += (bytes + 255) & ~(size_t)255;
        return r;
    };
    float* st      = (float*)alloc((size_t)N * 512 * 4);
    float* act     = (float*)alloc((size_t)N * 256 * 4);
    float* logits  = (float*)alloc((size_t)N * NCLS * 4);
    int*   cnt     = (int*)alloc((size_t)N * 4);
    int*   offs    = (int*)alloc((size_t)(N + 1) * 4);
    int*   cursor  = (int*)alloc((size_t)N * 4);
    float* invc    = (float*)alloc((size_t)N * 4);
    int*   csr_src = (int*)alloc((size_t)E * 4);
    float* csr_w   = (float*)alloc((size_t)E * 4);

    hipMemsetAsync(cnt, 0, (size_t)N * 4, stream);
    hipMemsetAsync(logits, 0, (size_t)N * NCLS * 4, stream);

    hist_kernel<<<(E + 255) / 256, 256, 0, stream>>>(dst, cnt, E);
    scan_kernel<<<1, 1024, 0, stream>>>(cnt, offs, invc, N);
    cursor_init<<<(N + 255) / 256, 256, 0, stream>>>(offs, cursor, N);
    scatter_kernel<<<(E + 255) / 256, 256, 0, stream>>>(src, dst, ew, cursor, csr_src, csr_w, E);

    dim3 gemm_grid((N + 63) / 64, 8);

    // layer 1: input x [N,500], W1 [1000,256]
    gemm_concat<<<gemm_grid, 256, 0, stream>>>(x, W1, b1, st, N, INF_);
    agg_relu_kernel<<<N, 256, 0, stream>>>(st, offs, csr_src, csr_w, invc, act, N);
    logits_add_kernel<<<(N + 3) / 4, 256, 0, stream>>>(act, Wl, logits, N);

    // layer 2
    gemm_concat<<<gemm_grid, 256, 0, stream>>>(act, W2, b2, st, N, HID);
    agg_relu_kernel<<<N, 256, 0, stream>>>(st, offs, csr_src, csr_w, invc, act, N);
    logits_add_kernel<<<(N + 3) / 4, 256, 0, stream>>>(act, Wl + (size_t)HID * NCLS, logits, N);

    // layer 3
    gemm_concat<<<gemm_grid, 256, 0, stream>>>(act, W3, b3, st, N, HID);
    agg_relu_kernel<<<N, 256, 0, stream>>>(st, offs, csr_src, csr_w, invc, act, N);
    logits_add_kernel<<<(N + 3) / 4, 256, 0, stream>>>(act, Wl + (size_t)2 * HID * NCLS, logits, N);

    logsoftmax_kernel<<<(N + 255) / 256, 256, 0, stream>>>(logits, bl, out, N);
}

// Round 2
// 1604.822 us; speedup vs baseline: 2.0070x; 2.0070x over previous
//
#include <hip/hip_runtime.h>
#include <hip/hip_bf16.h>

#define NN 89250
#define NE 899756
#define INF_ 500
#define HID 256
#define NCLS 7

typedef __attribute__((ext_vector_type(8))) short bf16x8;
typedef __attribute__((ext_vector_type(4))) float f32x4;

#define GL2LDS16(gp, lp)                                                        \
    __builtin_amdgcn_global_load_lds(                                           \
        (const __attribute__((address_space(1))) void*)(gp),                    \
        (__attribute__((address_space(3))) void*)(lp), 16, 0, 0)

static __device__ __forceinline__ unsigned short bf16bits(float f) {
    __hip_bfloat16 h = __float2bfloat16(f);
    return *reinterpret_cast<unsigned short*>(&h);
}

// ---------------- CSR build ----------------
__global__ void hist_kernel(const int* __restrict__ dst, int* __restrict__ cnt, int E) {
    int e = blockIdx.x * 256 + threadIdx.x;
    if (e < E) atomicAdd(&cnt[dst[e]], 1);
}

__global__ __launch_bounds__(1024) void scan_kernel(const int* __restrict__ cnt,
                                                    int* __restrict__ offs,
                                                    float* __restrict__ invc, int N) {
    __shared__ int sd[1024];
    __shared__ int s_run;
    int tid = threadIdx.x;
    if (tid == 0) s_run = 0;
    __syncthreads();
    int nChunks = (N + 1023) / 1024;
    for (int ch = 0; ch < nChunks; ch++) {
        int i = ch * 1024 + tid;
        int v = (i < N) ? cnt[i] : 0;
        sd[tid] = v;
        __syncthreads();
        for (int off = 1; off < 1024; off <<= 1) {
            int add = (tid >= off) ? sd[tid - off] : 0;
            __syncthreads();
            sd[tid] += add;
            __syncthreads();
        }
        int incl = sd[tid];
        int run = s_run;
        if (i < N) {
            offs[i] = run + incl - v;
            invc[i] = 1.0f / fmaxf((float)v, 1.0f);
        }
        __syncthreads();
        if (tid == 1023) s_run = run + sd[1023];
        __syncthreads();
    }
    if (tid == 0) offs[N] = s_run;
}

__global__ void cursor_init(const int* __restrict__ offs, int* __restrict__ cursor, int N) {
    int i = blockIdx.x * 256 + threadIdx.x;
    if (i < N) cursor[i] = offs[i];
}

__global__ void scatter_kernel(const int* __restrict__ src, const int* __restrict__ dst,
                               const float* __restrict__ w, int* __restrict__ cursor,
                               int* __restrict__ csr_src, float* __restrict__ csr_w, int E) {
    int e = blockIdx.x * 256 + threadIdx.x;
    if (e < E) {
        int d = dst[e];
        int pos = atomicAdd(&cursor[d], 1);
        csr_src[pos] = src[e];
        csr_w[pos] = w[e];
    }
}

// ---------------- conversions ----------------
// x [N,500] f32 -> xb [N,512] bf16 (cols 500..511 zero)
__global__ void conv_x_kernel(const float* __restrict__ x, __hip_bfloat16* __restrict__ xb) {
    long long idx = (long long)blockIdx.x * 256 + threadIdx.x;  // over N*128 float4-slots
    if (idx >= (long long)NN * 128) return;
    int row = (int)(idx >> 7), slot = (int)(idx & 127);
    float4 v = make_float4(0.f, 0.f, 0.f, 0.f);
    if (slot < 125) v = *(const float4*)&x[(size_t)row * 500 + slot * 4];
    __hip_bfloat16* o = xb + (size_t)row * 512 + slot * 4;
    o[0] = __float2bfloat16(v.x);
    o[1] = __float2bfloat16(v.y);
    o[2] = __float2bfloat16(v.z);
    o[3] = __float2bfloat16(v.w);
}

// W [2K,256] f32 -> BT [512][Kp] bf16 pre-transposed; k >= K zero-padded
__global__ void conv_w_kernel(const float* __restrict__ W, __hip_bfloat16* __restrict__ BT,
                              int K, int Kp) {
    int idx = blockIdx.x * 256 + threadIdx.x;
    if (idx >= 512 * Kp) return;
    int j = idx / Kp, k = idx - j * Kp;
    float v = (k < K) ? W[(size_t)(k + ((j >= 256) ? K : 0)) * 256 + (j & 255)] : 0.f;
    BT[idx] = __float2bfloat16(v);
}

// ---------------- MFMA GEMM ----------------
// C[N,512] = A[N,Kp] @ B where BT [512][Kp] holds B pre-transposed.
// cols 0..255  -> S (f32, +bias)   cols 256..511 -> T (bf16)
__global__ __launch_bounds__(256, 2) void gemm_mfma(
    const __hip_bfloat16* __restrict__ A, const __hip_bfloat16* __restrict__ BT,
    const float* __restrict__ bias, float* __restrict__ S,
    __hip_bfloat16* __restrict__ T, int N, int K) {
    __shared__ short lA[128 * 64];
    __shared__ short lB[128 * 64];
    int tid = threadIdx.x;
    int row0 = blockIdx.x * 128;
    int col0 = blockIdx.y * 128;  // 0,128,256,384
    int w = tid >> 6, l = tid & 63;
    int wm = (w >> 1) * 64, wn = (w & 1) * 64;
    int lr = l & 15, lk = (l >> 4) * 8;

    const char* gA[4];
    const char* gB[4];
    int ls[4];
#pragma unroll
    for (int p = 0; p < 4; p++) {
        int s = tid + p * 256;
        int r = s >> 3, c = s & 7;
        int ga_row = row0 + r;
        if (ga_row > N - 1) ga_row = N - 1;  // clamp: garbage rows never stored
        gA[p] = (const char*)A + (size_t)ga_row * K * 2 + c * 16;
        gB[p] = (const char*)BT + (size_t)(col0 + r) * K * 2 + c * 16;
        ls[p] = s * 16;
    }

    f32x4 acc[4][4];
#pragma unroll
    for (int m = 0; m < 4; m++)
#pragma unroll
        for (int n = 0; n < 4; n++) acc[m][n] = (f32x4){0.f, 0.f, 0.f, 0.f};

    int KT = K >> 6;
    for (int kt = 0; kt < KT; kt++) {
        size_t koff = (size_t)kt * 128;  // 64 bf16 = 128 bytes
#pragma unroll
        for (int p = 0; p < 4; p++) GL2LDS16(gA[p] + koff, (char*)lA + ls[p]);
#pragma unroll
        for (int p = 0; p < 4; p++) GL2LDS16(gB[p] + koff, (char*)lB + ls[p]);
        __syncthreads();
#pragma unroll
        for (int kk = 0; kk < 64; kk += 32) {
            bf16x8 af[4], bfr[4];
#pragma unroll
            for (int m = 0; m < 4; m++)
                af[m] = *(const bf16x8*)&lA[(wm + m * 16 + lr) * 64 + kk + lk];
#pragma unroll
            for (int n = 0; n < 4; n++)
                bfr[n] = *(const bf16x8*)&lB[(wn + n * 16 + lr) * 64 + kk + lk];
#pragma unroll
            for (int m = 0; m < 4; m++)
#pragma unroll
                for (int n = 0; n < 4; n++)
                    acc[m][n] = __builtin_amdgcn_mfma_f32_16x16x32_bf16(af[m], bfr[n],
                                                                        acc[m][n], 0, 0, 0);
        }
        __syncthreads();
    }

    int crow_base = row0 + wm + (l >> 4) * 4;
    bool isT = (col0 >= 256);
#pragma unroll
    for (int n = 0; n < 4; n++) {
        int col = col0 + wn + n * 16 + lr;
        float bv = isT ? 0.f : bias[col];
#pragma unroll
        for (int m = 0; m < 4; m++) {
#pragma unroll
            for (int r = 0; r < 4; r++) {
                int row = crow_base + m * 16 + r;
                if (row < N) {
                    float v = acc[m][n][r] + bv;
                    if (isT)
                        T[(size_t)row * 256 + (col - 256)] = __float2bfloat16(v);
                    else
                        S[(size_t)row * 256 + col] = v;
                }
            }
        }
    }
}

// ---------------- aggregate + relu ----------------
__global__ __launch_bounds__(256) void agg_relu_kernel(
    const float* __restrict__ S, const __hip_bfloat16* __restrict__ T,
    const int* __restrict__ offs, const int* __restrict__ csr_src,
    const float* __restrict__ csr_w, const float* __restrict__ invc,
    __hip_bfloat16* __restrict__ act, int N) {
    int n = blockIdx.x;
    int f = threadIdx.x;
    int beg = offs[n], end = offs[n + 1];
    float acc = 0.f;
    for (int j = beg; j < end; j++) {
        int s = csr_src[j];
        float w = csr_w[j];
        acc += __bfloat162float(T[(size_t)s * 256 + f]) * w;
    }
    float v = S[(size_t)n * 256 + f] + acc * invc[n];
    act[(size_t)n * 256 + f] = __float2bfloat16(fmaxf(v, 0.f));
}

// ---------------- logits += act @ Wl_chunk ----------------
__global__ __launch_bounds__(256) void logits_add_kernel(
    const __hip_bfloat16* __restrict__ act, const float* __restrict__ Wlc,
    float* __restrict__ logits, int N) {
    __shared__ float sW[HID * NCLS];
    int tid = threadIdx.x;
    for (int idx = tid; idx < HID * NCLS; idx += 256) sW[idx] = Wlc[idx];
    __syncthreads();
    int wave = tid >> 6, lane = tid & 63;
    int n = blockIdx.x * 4 + wave;
    if (n >= N) return;
    float p[NCLS] = {};
#pragma unroll
    for (int r = 0; r < 4; r++) {
        int fidx = r * 64 + lane;
        float a = __bfloat162float(act[(size_t)n * HID + fidx]);
#pragma unroll
        for (int c = 0; c < NCLS; c++) p[c] += a * sW[fidx * NCLS + c];
    }
#pragma unroll
    for (int c = 0; c < NCLS; c++) {
#pragma unroll
        for (int off = 32; off >= 1; off >>= 1) p[c] += __shfl_xor(p[c], off);
    }
    if (lane < NCLS) logits[(size_t)n * NCLS + lane] += p[lane];
}

// ---------------- final log_softmax ----------------
__global__ void logsoftmax_kernel(const float* __restrict__ logits, const float* __restrict__ bl,
                                  float* __restrict__ out, int N) {
    int n = blockIdx.x * 256 + threadIdx.x;
    if (n >= N) return;
    float l[NCLS];
    float m = -1e30f;
#pragma unroll
    for (int c = 0; c < NCLS; c++) {
        l[c] = logits[(size_t)n * NCLS + c] + bl[c];
        m = fmaxf(m, l[c]);
    }
    float s = 0.f;
#pragma unroll
    for (int c = 0; c < NCLS; c++) s += expf(l[c] - m);
    float lse = m + logf(s);
#pragma unroll
    for (int c = 0; c < NCLS; c++) out[(size_t)n * NCLS + c] = l[c] - lse;
}

extern "C" void kernel_launch(void* const* d_in, const int* in_sizes, int n_in,
                              void* d_out, int out_size, void* d_ws, size_t ws_size,
                              hipStream_t stream) {
    const float* x  = (const float*)d_in[0];
    const int*   ei = (const int*)d_in[1];
    const float* ew = (const float*)d_in[2];
    const float* W1 = (const float*)d_in[3];
    const float* b1 = (const float*)d_in[4];
    const float* W2 = (const float*)d_in[5];
    const float* b2 = (const float*)d_in[6];
    const float* W3 = (const float*)d_in[7];
    const float* b3 = (const float*)d_in[8];
    const float* Wl = (const float*)d_in[9];
    const float* bl = (const float*)d_in[10];
    float* out = (float*)d_out;

    const int N = NN, E = NE;
    const int* src = ei;
    const int* dst = ei + E;

    char* p = (char*)d_ws;
    auto alloc = [&](size_t bytes) {
        void* r = (void*)p;
        p += (bytes + 255) & ~(size_t)255;
        return r;
    };
    float*          S      = (float*)alloc((size_t)N * 256 * 4);
    __hip_bfloat16* T      = (__hip_bfloat16*)alloc((size_t)N * 256 * 2);
    __hip_bfloat16* act    = (__hip_bfloat16*)alloc((size_t)N * 256 * 2);
    __hip_bfloat16* xbf    = (__hip_bfloat16*)alloc((size_t)N * 512 * 2);
    __hip_bfloat16* B1T    = (__hip_bfloat16*)alloc((size_t)512 * 512 * 2);
    __hip_bfloat16* B2T    = (__hip_bfloat16*)alloc((size_t)512 * 256 * 2);
    __hip_bfloat16* B3T    = (__hip_bfloat16*)alloc((size_t)512 * 256 * 2);
    float*          logits = (float*)alloc((size_t)N * NCLS * 4);
    int*            cnt    = (int*)alloc((size_t)N * 4);
    int*            offs   = (int*)alloc((size_t)(N + 1) * 4);
    int*            cursor = (int*)alloc((size_t)N * 4);
    float*          invc   = (float*)alloc((size_t)N * 4);
    int*            csr_src = (int*)alloc((size_t)E * 4);
    float*          csr_w   = (float*)alloc((size_t)E * 4);

    hipMemsetAsync(cnt, 0, (size_t)N * 4, stream);
    hipMemsetAsync(logits, 0, (size_t)N * NCLS * 4, stream);

    // CSR build
    hist_kernel<<<(E + 255) / 256, 256, 0, stream>>>(dst, cnt, E);
    scan_kernel<<<1, 1024, 0, stream>>>(cnt, offs, invc, N);
    cursor_init<<<(N + 255) / 256, 256, 0, stream>>>(offs, cursor, N);
    scatter_kernel<<<(E + 255) / 256, 256, 0, stream>>>(src, dst, ew, cursor, csr_src, csr_w, E);

    // conversions
    conv_x_kernel<<<(int)(((long long)N * 128 + 255) / 256), 256, 0, stream>>>(x, xbf);
    conv_w_kernel<<<(512 * 512 + 255) / 256, 256, 0, stream>>>(W1, B1T, INF_, 512);
    conv_w_kernel<<<(512 * 256 + 255) / 256, 256, 0, stream>>>(W2, B2T, HID, 256);
    conv_w_kernel<<<(512 * 256 + 255) / 256, 256, 0, stream>>>(W3, B3T, HID, 256);

    dim3 ggrid((N + 127) / 128, 4);

    // layer 1
    gemm_mfma<<<ggrid, 256, 0, stream>>>(xbf, B1T, b1, S, T, N, 512);
    agg_relu_kernel<<<N, 256, 0, stream>>>(S, T, offs, csr_src, csr_w, invc, act, N);
    logits_add_kernel<<<(N + 3) / 4, 256, 0, stream>>>(act, Wl, logits, N);

    // layer 2
    gemm_mfma<<<ggrid, 256, 0, stream>>>(act, B2T, b2, S, T, N, 256);
    agg_relu_kernel<<<N, 256, 0, stream>>>(S, T, offs, csr_src, csr_w, invc, act, N);
    logits_add_kernel<<<(N + 3) / 4, 256, 0, stream>>>(act, Wl + (size_t)HID * NCLS, logits, N);

    // layer 3
    gemm_mfma<<<ggrid, 256, 0, stream>>>(act, B3T, b3, S, T, N, 256);
    agg_relu_kernel<<<N, 256, 0, stream>>>(S, T, offs, csr_src, csr_w, invc, act, N);
    logits_add_kernel<<<(N + 3) / 4, 256, 0, stream>>>(act, Wl + (size_t)2 * HID * NCLS, logits, N);

    logsoftmax_kernel<<<(N + 255) / 256, 256, 0, stream>>>(logits, bl, out, N);
}

// Round 3
// 975.945 us; speedup vs baseline: 3.3003x; 1.6444x over previous
//
#include <hip/hip_runtime.h>
#include <hip/hip_bf16.h>

#define NN 89250
#define NE 899756
#define INF_ 500
#define HID 256
#define NCLS 7

typedef __attribute__((ext_vector_type(8))) short bf16x8;
typedef __attribute__((ext_vector_type(4))) float f32x4;

#define GL2LDS16(gp, lp)                                                        \
    __builtin_amdgcn_global_load_lds(                                           \
        (const __attribute__((address_space(1))) void*)(gp),                    \
        (__attribute__((address_space(3))) void*)(lp), 16, 0, 0)

static __device__ __forceinline__ float b2f(short s) {
    union { unsigned int u; float f; } v;
    v.u = ((unsigned int)(unsigned short)s) << 16;
    return v.f;
}

// ---------------- CSR build ----------------
__global__ void hist_kernel(const int* __restrict__ dst, int* __restrict__ cnt, int E) {
    int e = blockIdx.x * 256 + threadIdx.x;
    if (e < E) atomicAdd(&cnt[dst[e]], 1);
}

// 3-pass scan: 1024 elems per block
__global__ __launch_bounds__(256) void scan1_kernel(const int* __restrict__ cnt,
                                                    int* __restrict__ loc,
                                                    int* __restrict__ bsum, int N) {
    __shared__ int sd[256];
    int b = blockIdx.x, tid = threadIdx.x;
    int base = b * 1024 + tid * 4;
    int v[4];
    int sum = 0;
#pragma unroll
    for (int k = 0; k < 4; k++) {
        int i = base + k;
        v[k] = (i < N) ? cnt[i] : 0;
        sum += v[k];
    }
    sd[tid] = sum;
    __syncthreads();
    for (int off = 1; off < 256; off <<= 1) {
        int add = (tid >= off) ? sd[tid - off] : 0;
        __syncthreads();
        sd[tid] += add;
        __syncthreads();
    }
    int run = sd[tid] - sum;  // exclusive
    if (tid == 255) bsum[b] = sd[255];
#pragma unroll
    for (int k = 0; k < 4; k++) {
        int i = base + k;
        if (i < N) loc[i] = run;
        run += v[k];
    }
}

__global__ __launch_bounds__(256) void scan2_kernel(int* __restrict__ bsum,
                                                    int* __restrict__ total, int nb) {
    __shared__ int sd[256];
    int tid = threadIdx.x;
    int v = (tid < nb) ? bsum[tid] : 0;
    sd[tid] = v;
    __syncthreads();
    for (int off = 1; off < 256; off <<= 1) {
        int add = (tid >= off) ? sd[tid - off] : 0;
        __syncthreads();
        sd[tid] += add;
        __syncthreads();
    }
    if (tid < nb) bsum[tid] = sd[tid] - v;
    if (tid == 255) *total = sd[255];
}

__global__ void scan3_kernel(const int* __restrict__ cnt, const int* __restrict__ loc,
                             const int* __restrict__ bsum, const int* __restrict__ total,
                             int* __restrict__ offs, int* __restrict__ cursor,
                             float* __restrict__ invc, int N) {
    int i = blockIdx.x * 256 + threadIdx.x;
    if (i < N) {
        int o = loc[i] + bsum[i >> 10];
        offs[i] = o;
        cursor[i] = o;
        invc[i] = 1.0f / fmaxf((float)cnt[i], 1.0f);
    }
    if (i == 0) offs[N] = *total;
}

__global__ void scatter_kernel(const int* __restrict__ src, const int* __restrict__ dst,
                               const float* __restrict__ w, int* __restrict__ cursor,
                               int* __restrict__ csr_src, float* __restrict__ csr_w, int E) {
    int e = blockIdx.x * 256 + threadIdx.x;
    if (e < E) {
        int d = dst[e];
        int pos = atomicAdd(&cursor[d], 1);
        csr_src[pos] = src[e];
        csr_w[pos] = w[e];
    }
}

// ---------------- conversions ----------------
__global__ void conv_x_kernel(const float* __restrict__ x, __hip_bfloat16* __restrict__ xb) {
    long long idx = (long long)blockIdx.x * 256 + threadIdx.x;
    if (idx >= (long long)NN * 128) return;
    int row = (int)(idx >> 7), slot = (int)(idx & 127);
    float4 v = make_float4(0.f, 0.f, 0.f, 0.f);
    if (slot < 125) v = *(const float4*)&x[(size_t)row * 500 + slot * 4];
    __hip_bfloat16* o = xb + (size_t)row * 512 + slot * 4;
    o[0] = __float2bfloat16(v.x);
    o[1] = __float2bfloat16(v.y);
    o[2] = __float2bfloat16(v.z);
    o[3] = __float2bfloat16(v.w);
}

__global__ void conv_w_kernel(const float* __restrict__ W, __hip_bfloat16* __restrict__ BT,
                              int K, int Kp) {
    int idx = blockIdx.x * 256 + threadIdx.x;
    if (idx >= 512 * Kp) return;
    int j = idx / Kp, k = idx - j * Kp;
    float v = (k < K) ? W[(size_t)(k + ((j >= 256) ? K : 0)) * 256 + (j & 255)] : 0.f;
    BT[idx] = __float2bfloat16(v);
}

// ---------------- MFMA GEMM ----------------
__global__ __launch_bounds__(256, 2) void gemm_mfma(
    const __hip_bfloat16* __restrict__ A, const __hip_bfloat16* __restrict__ BT,
    const float* __restrict__ bias, float* __restrict__ S,
    __hip_bfloat16* __restrict__ T, int N, int K) {
    __shared__ short lA[128 * 64];
    __shared__ short lB[128 * 64];
    int tid = threadIdx.x;
    int row0 = blockIdx.x * 128;
    int col0 = blockIdx.y * 128;
    int w = tid >> 6, l = tid & 63;
    int wm = (w >> 1) * 64, wn = (w & 1) * 64;
    int lr = l & 15, lk = (l >> 4) * 8;

    const char* gA[4];
    const char* gB[4];
    int ls[4];
#pragma unroll
    for (int p = 0; p < 4; p++) {
        int s = tid + p * 256;
        int r = s >> 3, c = s & 7;
        int ga_row = row0 + r;
        if (ga_row > N - 1) ga_row = N - 1;
        gA[p] = (const char*)A + (size_t)ga_row * K * 2 + c * 16;
        gB[p] = (const char*)BT + (size_t)(col0 + r) * K * 2 + c * 16;
        ls[p] = s * 16;
    }

    f32x4 acc[4][4];
#pragma unroll
    for (int m = 0; m < 4; m++)
#pragma unroll
        for (int n = 0; n < 4; n++) acc[m][n] = (f32x4){0.f, 0.f, 0.f, 0.f};

    int KT = K >> 6;
    for (int kt = 0; kt < KT; kt++) {
        size_t koff = (size_t)kt * 128;
#pragma unroll
        for (int p = 0; p < 4; p++) GL2LDS16(gA[p] + koff, (char*)lA + ls[p]);
#pragma unroll
        for (int p = 0; p < 4; p++) GL2LDS16(gB[p] + koff, (char*)lB + ls[p]);
        __syncthreads();
#pragma unroll
        for (int kk = 0; kk < 64; kk += 32) {
            bf16x8 af[4], bfr[4];
#pragma unroll
            for (int m = 0; m < 4; m++)
                af[m] = *(const bf16x8*)&lA[(wm + m * 16 + lr) * 64 + kk + lk];
#pragma unroll
            for (int n = 0; n < 4; n++)
                bfr[n] = *(const bf16x8*)&lB[(wn + n * 16 + lr) * 64 + kk + lk];
#pragma unroll
            for (int m = 0; m < 4; m++)
#pragma unroll
                for (int n = 0; n < 4; n++)
                    acc[m][n] = __builtin_amdgcn_mfma_f32_16x16x32_bf16(af[m], bfr[n],
                                                                        acc[m][n], 0, 0, 0);
        }
        __syncthreads();
    }

    int crow_base = row0 + wm + (l >> 4) * 4;
    bool isT = (col0 >= 256);
#pragma unroll
    for (int n = 0; n < 4; n++) {
        int col = col0 + wn + n * 16 + lr;
        float bv = isT ? 0.f : bias[col];
#pragma unroll
        for (int m = 0; m < 4; m++) {
#pragma unroll
            for (int r = 0; r < 4; r++) {
                int row = crow_base + m * 16 + r;
                if (row < N) {
                    float v = acc[m][n][r] + bv;
                    if (isT)
                        T[(size_t)row * 256 + (col - 256)] = __float2bfloat16(v);
                    else
                        S[(size_t)row * 256 + col] = v;
                }
            }
        }
    }
}

// ---------------- fused aggregate + relu + logits partial ----------------
// 8 nodes/block, 32 lanes/node, lane owns 8 features. 4-deep edge unroll.
__global__ __launch_bounds__(256) void agg_fused_kernel(
    const float* __restrict__ S, const __hip_bfloat16* __restrict__ T,
    const int* __restrict__ offs, const int* __restrict__ csr_src,
    const float* __restrict__ csr_w, const float* __restrict__ invc,
    const float* __restrict__ Wlc, __hip_bfloat16* __restrict__ act,
    float* __restrict__ logits, int N) {
    __shared__ float sW[HID * NCLS];
    for (int i = threadIdx.x; i < HID * NCLS; i += 256) sW[i] = Wlc[i];
    __syncthreads();

    int g = threadIdx.x >> 5, t = threadIdx.x & 31;
    int n = blockIdx.x * 8 + g;
    if (n >= N) return;
    int beg = offs[n], end = offs[n + 1];

    float acc[8] = {};
    int j = beg;
    for (; j + 4 <= end; j += 4) {
        int s0 = csr_src[j], s1 = csr_src[j + 1], s2 = csr_src[j + 2], s3 = csr_src[j + 3];
        float w0 = csr_w[j], w1 = csr_w[j + 1], w2 = csr_w[j + 2], w3 = csr_w[j + 3];
        bf16x8 r0 = *(const bf16x8*)&T[(size_t)s0 * 256 + t * 8];
        bf16x8 r1 = *(const bf16x8*)&T[(size_t)s1 * 256 + t * 8];
        bf16x8 r2 = *(const bf16x8*)&T[(size_t)s2 * 256 + t * 8];
        bf16x8 r3 = *(const bf16x8*)&T[(size_t)s3 * 256 + t * 8];
#pragma unroll
        for (int k = 0; k < 8; k++) {
            acc[k] += b2f(r0[k]) * w0;
            acc[k] += b2f(r1[k]) * w1;
            acc[k] += b2f(r2[k]) * w2;
            acc[k] += b2f(r3[k]) * w3;
        }
    }
    for (; j < end; j++) {
        int s0 = csr_src[j];
        float w0 = csr_w[j];
        bf16x8 r0 = *(const bf16x8*)&T[(size_t)s0 * 256 + t * 8];
#pragma unroll
        for (int k = 0; k < 8; k++) acc[k] += b2f(r0[k]) * w0;
    }

    float ic = invc[n];
    const float* Srow = S + (size_t)n * 256 + t * 8;
    float4 sv0 = *(const float4*)&Srow[0];
    float4 sv1 = *(const float4*)&Srow[4];
    float a[8];
    a[0] = fmaxf(sv0.x + acc[0] * ic, 0.f);
    a[1] = fmaxf(sv0.y + acc[1] * ic, 0.f);
    a[2] = fmaxf(sv0.z + acc[2] * ic, 0.f);
    a[3] = fmaxf(sv0.w + acc[3] * ic, 0.f);
    a[4] = fmaxf(sv1.x + acc[4] * ic, 0.f);
    a[5] = fmaxf(sv1.y + acc[5] * ic, 0.f);
    a[6] = fmaxf(sv1.z + acc[6] * ic, 0.f);
    a[7] = fmaxf(sv1.w + acc[7] * ic, 0.f);

    bf16x8 ov;
#pragma unroll
    for (int k = 0; k < 8; k++) {
        __hip_bfloat16 h = __float2bfloat16(a[k]);
        ov[k] = *reinterpret_cast<short*>(&h);
    }
    *(bf16x8*)&act[(size_t)n * 256 + t * 8] = ov;

    // logits partial: p[c] = sum_f a[f] * Wlc[f][c]
    float pl[NCLS] = {};
#pragma unroll
    for (int k = 0; k < 8; k++) {
        int f = t * 8 + k;
        float av = a[k];
#pragma unroll
        for (int c = 0; c < NCLS; c++) pl[c] += av * sW[f * NCLS + c];
    }
#pragma unroll
    for (int c = 0; c < NCLS; c++) {
#pragma unroll
        for (int off = 16; off >= 1; off >>= 1) pl[c] += __shfl_xor(pl[c], off, 32);
    }
    if (t == 0) {
        float* lp = logits + (size_t)n * NCLS;
#pragma unroll
        for (int c = 0; c < NCLS; c++) lp[c] += pl[c];
    }
}

// ---------------- final log_softmax ----------------
__global__ void logsoftmax_kernel(const float* __restrict__ logits, const float* __restrict__ bl,
                                  float* __restrict__ out, int N) {
    int n = blockIdx.x * 256 + threadIdx.x;
    if (n >= N) return;
    float l[NCLS];
    float m = -1e30f;
#pragma unroll
    for (int c = 0; c < NCLS; c++) {
        l[c] = logits[(size_t)n * NCLS + c] + bl[c];
        m = fmaxf(m, l[c]);
    }
    float s = 0.f;
#pragma unroll
    for (int c = 0; c < NCLS; c++) s += expf(l[c] - m);
    float lse = m + logf(s);
#pragma unroll
    for (int c = 0; c < NCLS; c++) out[(size_t)n * NCLS + c] = l[c] - lse;
}

extern "C" void kernel_launch(void* const* d_in, const int* in_sizes, int n_in,
                              void* d_out, int out_size, void* d_ws, size_t ws_size,
                              hipStream_t stream) {
    const float* x  = (const float*)d_in[0];
    const int*   ei = (const int*)d_in[1];
    const float* ew = (const float*)d_in[2];
    const float* W1 = (const float*)d_in[3];
    const float* b1 = (const float*)d_in[4];
    const float* W2 = (const float*)d_in[5];
    const float* b2 = (const float*)d_in[6];
    const float* W3 = (const float*)d_in[7];
    const float* b3 = (const float*)d_in[8];
    const float* Wl = (const float*)d_in[9];
    const float* bl = (const float*)d_in[10];
    float* out = (float*)d_out;

    const int N = NN, E = NE;
    const int* src = ei;
    const int* dst = ei + E;

    char* p = (char*)d_ws;
    auto alloc = [&](size_t bytes) {
        void* r = (void*)p;
        p += (bytes + 255) & ~(size_t)255;
        return r;
    };
    float*          S      = (float*)alloc((size_t)N * 256 * 4);
    __hip_bfloat16* T      = (__hip_bfloat16*)alloc((size_t)N * 256 * 2);
    __hip_bfloat16* act    = (__hip_bfloat16*)alloc((size_t)N * 256 * 2);
    __hip_bfloat16* xbf    = (__hip_bfloat16*)alloc((size_t)N * 512 * 2);
    __hip_bfloat16* B1T    = (__hip_bfloat16*)alloc((size_t)512 * 512 * 2);
    __hip_bfloat16* B2T    = (__hip_bfloat16*)alloc((size_t)512 * 256 * 2);
    __hip_bfloat16* B3T    = (__hip_bfloat16*)alloc((size_t)512 * 256 * 2);
    float*          logits = (float*)alloc((size_t)N * NCLS * 4);
    int*            cnt    = (int*)alloc((size_t)N * 4);
    int*            offs   = (int*)alloc((size_t)(N + 1) * 4);
    int*            cursor = (int*)alloc((size_t)N * 4);
    float*          invc   = (float*)alloc((size_t)N * 4);
    int*            loc    = (int*)alloc((size_t)N * 4);
    int*            bsum   = (int*)alloc(256 * 4);
    int*            total  = (int*)alloc(4);
    int*            csr_src = (int*)alloc((size_t)E * 4);
    float*          csr_w   = (float*)alloc((size_t)E * 4);

    hipMemsetAsync(cnt, 0, (size_t)N * 4, stream);
    hipMemsetAsync(logits, 0, (size_t)N * NCLS * 4, stream);

    // CSR build
    int nb = (N + 1023) / 1024;
    hist_kernel<<<(E + 255) / 256, 256, 0, stream>>>(dst, cnt, E);
    scan1_kernel<<<nb, 256, 0, stream>>>(cnt, loc, bsum, N);
    scan2_kernel<<<1, 256, 0, stream>>>(bsum, total, nb);
    scan3_kernel<<<(N + 255) / 256, 256, 0, stream>>>(cnt, loc, bsum, total, offs, cursor, invc, N);
    scatter_kernel<<<(E + 255) / 256, 256, 0, stream>>>(src, dst, ew, cursor, csr_src, csr_w, E);

    // conversions
    conv_x_kernel<<<(int)(((long long)N * 128 + 255) / 256), 256, 0, stream>>>(x, xbf);
    conv_w_kernel<<<(512 * 512 + 255) / 256, 256, 0, stream>>>(W1, B1T, INF_, 512);
    conv_w_kernel<<<(512 * 256 + 255) / 256, 256, 0, stream>>>(W2, B2T, HID, 256);
    conv_w_kernel<<<(512 * 256 + 255) / 256, 256, 0, stream>>>(W3, B3T, HID, 256);

    dim3 ggrid((N + 127) / 128, 4);
    int agrid = (N + 7) / 8;

    // layer 1
    gemm_mfma<<<ggrid, 256, 0, stream>>>(xbf, B1T, b1, S, T, N, 512);
    agg_fused_kernel<<<agrid, 256, 0, stream>>>(S, T, offs, csr_src, csr_w, invc,
                                                Wl, act, logits, N);
    // layer 2
    gemm_mfma<<<ggrid, 256, 0, stream>>>(act, B2T, b2, S, T, N, 256);
    agg_fused_kernel<<<agrid, 256, 0, stream>>>(S, T, offs, csr_src, csr_w, invc,
                                                Wl + (size_t)HID * NCLS, act, logits, N);
    // layer 3
    gemm_mfma<<<ggrid, 256, 0, stream>>>(act, B3T, b3, S, T, N, 256);
    agg_fused_kernel<<<agrid, 256, 0, stream>>>(S, T, offs, csr_src, csr_w, invc,
                                                Wl + (size_t)2 * HID * NCLS, act, logits, N);

    logsoftmax_kernel<<<(N + 255) / 256, 256, 0, stream>>>(logits, bl, out, N);
}